// Round 2
// baseline (593.261 us; speedup 1.0000x reference)
//
#include <hip/hip_runtime.h>

#define NB 8
#define CH 128
#define HH 160
#define WW 160
// Scan-state storage map (per column/row of 160 scan positions):
//   rows [0,48)   -> global spill (re-read via 16-deep ring)
//   rows [48,96)  -> 48 float2 registers (static-indexed, segment-unrolled)
//   rows [96,160) -> 64-row LDS = 32768 B -> 5 blocks/CU = 160 KB exact fit

// DPP full-wave shifts; bound_ctrl=1 zero-fills out-of-wave = channel zero-padding.
__device__ __forceinline__ float dpp_up1(float x) {   // lane i <- lane i-1, lane 0 <- 0
    return __int_as_float(__builtin_amdgcn_update_dpp(0, __float_as_int(x), 0x138, 0xF, 0xF, true));
}
__device__ __forceinline__ float dpp_dn1(float x) {   // lane i <- lane i+1, lane 63 <- 0
    return __int_as_float(__builtin_amdgcn_update_dpp(0, __float_as_int(x), 0x130, 0xF, 0xF, true));
}

// 9-tap conv along channels; thread t owns channels 2t,2t+1. 3x3-tap trees (chain: 3 fma + 2 add).
__device__ __forceinline__ float2 conv9(float2 p, const float* w, float b) {
    float m1x = dpp_up1(p.x), m1y = dpp_up1(p.y);
    float m2x = dpp_up1(m1x), m2y = dpp_up1(m1y);
    float p1x = dpp_dn1(p.x), p1y = dpp_dn1(p.y);
    float p2x = dpp_dn1(p1x), p2y = dpp_dn1(p1y);
    float e0=m2x,e1=m2y,e2=m1x,e3=m1y,e4=p.x,e5=p.y,e6=p1x,e7=p1y,e8=p2x,e9=p2y;
    float ax = fmaf(w[0], e0, b);       ax = fmaf(w[3], e3, ax); ax = fmaf(w[6], e6, ax);
    float bx = w[1]*e1;                 bx = fmaf(w[4], e4, bx); bx = fmaf(w[7], e7, bx);
    float cx = w[2]*e2;                 cx = fmaf(w[5], e5, cx); cx = fmaf(w[8], e8, cx);
    float ay = fmaf(w[0], e1, b);       ay = fmaf(w[3], e4, ay); ay = fmaf(w[6], e7, ay);
    float by = w[1]*e2;                 by = fmaf(w[4], e5, by); by = fmaf(w[7], e8, by);
    float cy = w[2]*e3;                 cy = fmaf(w[5], e6, cy); cy = fmaf(w[8], e9, cy);
    return make_float2((ax + bx) + cx, (ay + by) + cy);
}

__device__ __forceinline__ void scan_step(float2& st, float2 xr, const float* w, float b) {
    float2 cv = conv9(st, w, b);
    st.x = fmaxf(cv.x, 0.f) + xr.x;
    st.y = fmaxf(cv.y, 0.f) + xr.y;
}

// K0: NCHW -> NHWC. Tile: 32 c x 128 p. Reads float4 (512B/row), writes float2 (128B segs).
__global__ __launch_bounds__(256) void k0_transpose(const float* __restrict__ x,
                                                    float* __restrict__ A) {
    __shared__ float t[32][132];   // 132: float4-aligned row, breaks worst banking
    int p0 = blockIdx.x * 128;
    int c0 = blockIdx.y * 32;
    int n  = blockIdx.z;
    int tid = threadIdx.x;
    const float* xn = x + (size_t)n * CH * HH * WW;
    float* An = A + (size_t)n * HH * WW * CH;
    #pragma unroll
    for (int j = 0; j < 4; j++) {
        int c = j*8 + tid/32;
        int q4 = (tid%32)*4;
        float4 v = *(const float4*)(xn + (size_t)(c0 + c) * (HH*WW) + p0 + q4);
        *(float4*)&t[c][q4] = v;
    }
    __syncthreads();
    #pragma unroll
    for (int j = 0; j < 8; j++) {
        int p  = j*16 + tid/16;
        int cq = (tid%16)*2;
        float2 v = make_float2(t[cq][p], t[cq+1][p]);
        *(float2*)(An + (size_t)(p0 + p) * CH + c0 + cq) = v;
    }
}

// K1: fused down+up scan over H, in-place on A. 1 wave per (n,w) column; 5 blocks/CU.
__global__ __launch_bounds__(64, 2) void k1_vert(float* __restrict__ A,
        const float* __restrict__ wdp, const float* __restrict__ bdp,
        const float* __restrict__ wup, const float* __restrict__ bup) {
    __shared__ float lds[64][CH];   // rows h in [96,160): x at [r][lane], y at [r][64+lane]
    int lane = threadIdx.x;
    int w = blockIdx.x, n = blockIdx.y;
    float wd[9], wu[9];
    #pragma unroll
    for (int j = 0; j < 9; j++) { wd[j] = wdp[j]; wu[j] = wup[j]; }
    float bd = bdp[0], bu = bup[0];
    float* col = A + ((size_t)n * HH * WW + w) * CH + 2*lane;
    const size_t RS = (size_t)WW * CH;

    // ---- down: d[h] = relu(conv(d[h-1]))+x[h] ----
    float2 d;
    float2 rr[48];          // relu(d) rows 48..95, static-indexed
    float2 qf[16];
    #pragma unroll
    for (int i = 0; i < 16; i++) qf[i] = *(const float2*)(col + (size_t)i * RS);

    // Seg A: h 0..47 -> spill relu(d) in-place to global
    for (int hb = 0; hb < 48; hb += 16) {
        #pragma unroll
        for (int k = 0; k < 16; k++) {
            int h = hb + k;
            float2 xr = qf[k];
            qf[k] = *(const float2*)(col + (size_t)(h+16) * RS);   // h+16 <= 63
            if (h == 0) d = xr;
            else scan_step(d, xr, wd, bd);
            *(float2*)(col + (size_t)h * RS) = make_float2(fmaxf(d.x,0.f), fmaxf(d.y,0.f));
        }
    }
    // Seg B: h 48..95 -> registers
    #pragma unroll
    for (int seg = 0; seg < 3; seg++) {
        #pragma unroll
        for (int k = 0; k < 16; k++) {
            int h = 48 + seg*16 + k;
            float2 xr = qf[k];
            qf[k] = *(const float2*)(col + (size_t)(h+16) * RS);   // h+16 <= 111
            scan_step(d, xr, wd, bd);
            rr[seg*16 + k] = make_float2(fmaxf(d.x,0.f), fmaxf(d.y,0.f));
        }
    }
    // Seg C: h 96..159 -> LDS
    for (int hb = 96; hb < 160; hb += 16) {
        #pragma unroll
        for (int k = 0; k < 16; k++) {
            int h = hb + k;
            float2 xr = qf[k];
            if (h + 16 < HH) qf[k] = *(const float2*)(col + (size_t)(h+16) * RS);
            scan_step(d, xr, wd, bd);
            lds[h-96][lane]    = fmaxf(d.x,0.f);
            lds[h-96][64+lane] = fmaxf(d.y,0.f);
        }
    }

    // ---- up: u[s] = relu(conv(u[s-1]))+relu(d[159-s]) ----
    float2 u;
    float2 gq[16];
    // U1: s 0..63 (h 159..96) from LDS (reads batch-hoisted per unrolled chunk)
    for (int sb = 0; sb < 64; sb += 16) {
        #pragma unroll
        for (int k = 0; k < 16; k++) {
            int s = sb + k, h = 159 - s, r = h - 96;
            float2 t2 = make_float2(lds[r][lane], lds[r][64+lane]);
            if (sb == 0 && k == 0) u = t2;
            else scan_step(u, t2, wu, bu);
            *(float2*)(col + (size_t)h * RS) = u;
        }
    }
    // U2: s 64..111 (h 95..48) from registers; prime global ring during seg 0
    #pragma unroll
    for (int seg = 0; seg < 3; seg++) {
        #pragma unroll
        for (int k = 0; k < 16; k++) {
            int h = 95 - seg*16 - k;
            float2 t2 = rr[h - 48];
            scan_step(u, t2, wu, bu);
            *(float2*)(col + (size_t)h * RS) = u;
            if (seg == 0) gq[k] = *(const float2*)(col + (size_t)(47-k) * RS);
        }
    }
    // U3: s 112..159 (h 47..0), 16-deep global ring
    for (int sb = 112; sb < 160; sb += 16) {
        #pragma unroll
        for (int k = 0; k < 16; k++) {
            int s = sb + k, h = 159 - s;
            float2 t2 = gq[k];
            int h2 = h - 16;
            if (h2 >= 0) gq[k] = *(const float2*)(col + (size_t)h2 * RS);
            scan_step(u, t2, wu, bu);
            *(float2*)(col + (size_t)h * RS) = u;
        }
    }
}

// K2: fused left+right scan over W + fused flip-transpose output.
// 1 wave per (n,h) row; 5 blocks/CU. Right-scan step s (w=159-s) is final value for
// out[n][c][159-h][s]; staged into LDS rows freed exactly as spill rows are consumed
// (row for step s = 63-(s mod 64)); flushed coalesced every 32 steps.
// XOR swizzle col^(row&31): per-row accesses stay lane permutations (free);
// transposed flush reads spread across banks (2-way = free).
__global__ __launch_bounds__(64, 2) void k2_horz(float* __restrict__ A,
        const float* __restrict__ wlp, const float* __restrict__ blp,
        const float* __restrict__ wrp, const float* __restrict__ brp,
        float* __restrict__ out) {
    __shared__ float lds[64][CH];
    int lane = threadIdx.x;
    int hp = blockIdx.x, n = blockIdx.y;
    float wA[9], wB[9];
    #pragma unroll
    for (int j = 0; j < 9; j++) { wA[j] = wlp[j]; wB[j] = wrp[j]; }
    float bA = blp[0], bB = brp[0];
    float* row0 = A + ((size_t)n * HH + hp) * WW * CH + 2*lane;
    const size_t PS = CH;

    // ---- left scan ----
    float2 l;
    float2 rr[48];
    float2 qf[16];
    #pragma unroll
    for (int i = 0; i < 16; i++) qf[i] = *(const float2*)(row0 + (size_t)i * PS);

    // Seg A: a 0..47 -> spill relu(l) in-place to global
    for (int ab = 0; ab < 48; ab += 16) {
        #pragma unroll
        for (int k = 0; k < 16; k++) {
            int a = ab + k;
            float2 xr = qf[k];
            qf[k] = *(const float2*)(row0 + (size_t)(a+16) * PS);
            xr.x = fmaxf(xr.x, 0.f); xr.y = fmaxf(xr.y, 0.f);
            if (a == 0) l = xr;
            else scan_step(l, xr, wA, bA);
            *(float2*)(row0 + (size_t)a * PS) = make_float2(fmaxf(l.x,0.f), fmaxf(l.y,0.f));
        }
    }
    // Seg B: a 48..95 -> registers
    #pragma unroll
    for (int seg = 0; seg < 3; seg++) {
        #pragma unroll
        for (int k = 0; k < 16; k++) {
            int a = 48 + seg*16 + k;
            float2 xr = qf[k];
            qf[k] = *(const float2*)(row0 + (size_t)(a+16) * PS);
            xr.x = fmaxf(xr.x, 0.f); xr.y = fmaxf(xr.y, 0.f);
            scan_step(l, xr, wA, bA);
            rr[seg*16 + k] = make_float2(fmaxf(l.x,0.f), fmaxf(l.y,0.f));
        }
    }
    // Seg C: a 96..159 -> LDS, swizzled
    for (int ab = 96; ab < 160; ab += 16) {
        #pragma unroll
        for (int k = 0; k < 16; k++) {
            int a = ab + k;
            float2 xr = qf[k];
            if (a + 16 < WW) qf[k] = *(const float2*)(row0 + (size_t)(a+16) * PS);
            xr.x = fmaxf(xr.x, 0.f); xr.y = fmaxf(xr.y, 0.f);
            scan_step(l, xr, wA, bA);
            int r = a - 96, sw = r & 31;
            lds[r][lane ^ sw]        = fmaxf(l.x,0.f);
            lds[r][64 + (lane ^ sw)] = fmaxf(l.y,0.f);
        }
    }

    // ---- right scan with fused flipped-transposed output ----
    float2 u;
    float2 gq[16];
    int ho  = HH - 1 - hp;
    int l31 = lane & 31;
    int hi  = lane >> 5;
    float* ob = out + ((size_t)(n * CH + hi) * HH + ho) * WW + l31;
    int jx = 31 - l31;
    const float* lp = &lds[0][0];

    // U1: s 0..63 (a 159..96) from LDS; staging overwrites the row just consumed
    for (int sb = 0; sb < 64; sb += 16) {
        #pragma unroll
        for (int k = 0; k < 16; k++) {
            int s = sb + k, r = 63 - s, sw = r & 31;
            int ci = lane ^ sw;
            float2 t2 = make_float2(lds[r][ci], lds[r][64+ci]);
            if (sb == 0 && k == 0) u = t2;
            else scan_step(u, t2, wB, bB);
            lds[r][ci]    = fmaxf(u.x, 0.f);
            lds[r][64+ci] = fmaxf(u.y, 0.f);
        }
        if (sb == 16 || sb == 48) {   // flush s-block [sb-16, sb+16)
            int jf = (sb == 16 ? 63 : 31) - l31;
            int pl = jf*128 + (hi << 6);
            int so = sb - 16;
            #pragma unroll
            for (int i = 0; i < 64; i++)
                ob[(size_t)(2*i) * (HH*WW) + so] = lp[pl + (i ^ jx)];
        }
    }
    // U2: s 64..111 (a 95..48) from registers; prime global ring in seg 0; flush after seg 1
    #pragma unroll
    for (int seg = 0; seg < 3; seg++) {
        #pragma unroll
        for (int k = 0; k < 16; k++) {
            int s = 64 + seg*16 + k;
            int a = 159 - s;
            float2 t2 = rr[a - 48];
            scan_step(u, t2, wB, bB);
            int js = 63 - 16*seg - k;   // = 127 - s
            int sw = js & 31;
            lds[js][lane ^ sw]        = fmaxf(u.x, 0.f);
            lds[js][64 + (lane ^ sw)] = fmaxf(u.y, 0.f);
            if (seg == 0) gq[k] = *(const float2*)(row0 + (size_t)(47-k) * PS);
        }
        if (seg == 1) {   // flush s-block [64,96): rows 63..32
            int jf = 63 - l31;
            int pl = jf*128 + (hi << 6);
            #pragma unroll
            for (int i = 0; i < 64; i++)
                ob[(size_t)(2*i) * (HH*WW) + 64] = lp[pl + (i ^ jx)];
        }
    }
    // U3: s 112..159 (a 47..0), 16-deep global ring; flushes after chunks 112 and 144
    for (int sb = 112; sb < 160; sb += 16) {
        #pragma unroll
        for (int k = 0; k < 16; k++) {
            int s = sb + k, a = 159 - s;
            float2 t2 = gq[k];
            int a2 = a - 16;
            if (a2 >= 0) gq[k] = *(const float2*)(row0 + (size_t)a2 * PS);
            scan_step(u, t2, wB, bB);
            int js = 63 - (s & 63);
            int sw = js & 31;
            lds[js][lane ^ sw]        = fmaxf(u.x, 0.f);
            lds[js][64 + (lane ^ sw)] = fmaxf(u.y, 0.f);
        }
        if (sb == 112) {   // flush s-block [96,128): rows 31..0
            int jf = 31 - l31;
            int pl = jf*128 + (hi << 6);
            #pragma unroll
            for (int i = 0; i < 64; i++)
                ob[(size_t)(2*i) * (HH*WW) + 96] = lp[pl + (i ^ jx)];
        }
        if (sb == 144) {   // flush s-block [128,160): rows 63..32
            int jf = 63 - l31;
            int pl = jf*128 + (hi << 6);
            #pragma unroll
            for (int i = 0; i < 64; i++)
                ob[(size_t)(2*i) * (HH*WW) + 128] = lp[pl + (i ^ jx)];
        }
    }
}

extern "C" void kernel_launch(void* const* d_in, const int* in_sizes, int n_in,
                              void* d_out, int out_size, void* d_ws, size_t ws_size,
                              hipStream_t stream) {
    (void)in_sizes; (void)n_in; (void)out_size; (void)ws_size;
    const float* x  = (const float*)d_in[0];
    const float* wd = (const float*)d_in[1];
    const float* bd = (const float*)d_in[2];
    const float* wu = (const float*)d_in[3];
    const float* bu = (const float*)d_in[4];
    const float* wl = (const float*)d_in[5];
    const float* bl = (const float*)d_in[6];
    const float* wr = (const float*)d_in[7];
    const float* br = (const float*)d_in[8];
    float* out = (float*)d_out;
    float* A   = (float*)d_ws;   // needs N*H*W*C*4 = 104,857,600 bytes

    dim3 g0(HH*WW/128, CH/32, NB), b0(256);
    k0_transpose<<<g0, b0, 0, stream>>>(x, A);

    dim3 g1(WW, NB), b1(64);
    k1_vert<<<g1, b1, 0, stream>>>(A, wd, bd, wu, bu);

    dim3 g2(HH, NB);
    k2_horz<<<g2, b1, 0, stream>>>(A, wl, bl, wr, br, out);
}

// Round 3
// 388.051 us; speedup vs baseline: 1.5288x; 1.5288x over previous
//
#include <hip/hip_runtime.h>

#define NB 8
#define CH 128
#define HH 160
#define WW 160
#define SPILL 100
#define LDS_ROWS 60   // rows [100..159] in LDS: 60*128*4 = 30720 B -> 5 blocks/CU
// Scan-state map per 160-position column/row:
//   [0,84)   -> global spill (re-read via the 16-deep tf ring)
//   [84,100) -> 16 float2 registers rr[16] (static-indexed, segment-specialized)
//   [100,160)-> 60-row LDS

// DPP full-wave shifts; bound_ctrl=1 zero-fills out-of-wave = channel zero-padding.
__device__ __forceinline__ float dpp_up1(float x) {   // lane i <- lane i-1, lane 0 <- 0
    return __int_as_float(__builtin_amdgcn_update_dpp(0, __float_as_int(x), 0x138, 0xF, 0xF, true));
}
__device__ __forceinline__ float dpp_dn1(float x) {   // lane i <- lane i+1, lane 63 <- 0
    return __int_as_float(__builtin_amdgcn_update_dpp(0, __float_as_int(x), 0x130, 0xF, 0xF, true));
}

// 9-tap conv along channels; thread t owns channels 2t,2t+1. 3x3-tap trees.
__device__ __forceinline__ float2 conv9(float2 p, const float* w, float b) {
    float m1x = dpp_up1(p.x), m1y = dpp_up1(p.y);
    float m2x = dpp_up1(m1x), m2y = dpp_up1(m1y);
    float p1x = dpp_dn1(p.x), p1y = dpp_dn1(p.y);
    float p2x = dpp_dn1(p1x), p2y = dpp_dn1(p1y);
    float e0=m2x,e1=m2y,e2=m1x,e3=m1y,e4=p.x,e5=p.y,e6=p1x,e7=p1y,e8=p2x,e9=p2y;
    float ax = fmaf(w[0], e0, b);       ax = fmaf(w[3], e3, ax); ax = fmaf(w[6], e6, ax);
    float bx = w[1]*e1;                 bx = fmaf(w[4], e4, bx); bx = fmaf(w[7], e7, bx);
    float cx = w[2]*e2;                 cx = fmaf(w[5], e5, cx); cx = fmaf(w[8], e8, cx);
    float ay = fmaf(w[0], e1, b);       ay = fmaf(w[3], e4, ay); ay = fmaf(w[6], e7, ay);
    float by = w[1]*e2;                 by = fmaf(w[4], e5, by); by = fmaf(w[7], e8, by);
    float cy = w[2]*e3;                 cy = fmaf(w[5], e6, cy); cy = fmaf(w[8], e9, cy);
    return make_float2((ax + bx) + cx, (ay + by) + cy);
}

__device__ __forceinline__ void scan_step(float2& st, float2 xr, const float* w, float b) {
    float2 cv = conv9(st, w, b);
    st.x = fmaxf(cv.x, 0.f) + xr.x;
    st.y = fmaxf(cv.y, 0.f) + xr.y;
}

// K0: NCHW -> NHWC. Tile: 32 c x 128 p. (unchanged from the 332 us version)
__global__ __launch_bounds__(256) void k0_transpose(const float* __restrict__ x,
                                                    float* __restrict__ A) {
    __shared__ float t[32][132];
    int p0 = blockIdx.x * 128;
    int c0 = blockIdx.y * 32;
    int n  = blockIdx.z;
    int tid = threadIdx.x;
    const float* xn = x + (size_t)n * CH * HH * WW;
    float* An = A + (size_t)n * HH * WW * CH;
    #pragma unroll
    for (int j = 0; j < 4; j++) {
        int c = j*8 + tid/32;
        int q4 = (tid%32)*4;
        float4 v = *(const float4*)(xn + (size_t)(c0 + c) * (HH*WW) + p0 + q4);
        *(float4*)&t[c][q4] = v;
    }
    __syncthreads();
    #pragma unroll
    for (int j = 0; j < 8; j++) {
        int p  = j*16 + tid/16;
        int cq = (tid%16)*2;
        float2 v = make_float2(t[cq][p], t[cq+1][p]);
        *(float2*)(An + (size_t)(p0 + p) * CH + c0 + cq) = v;
    }
}

// K1: fused down+up scan over H, in-place on A. 1 wave per (n,w) column; 5 blocks/CU.
__global__ __launch_bounds__(64) void k1_vert(float* __restrict__ A,
        const float* __restrict__ wdp, const float* __restrict__ bdp,
        const float* __restrict__ wup, const float* __restrict__ bup) {
    __shared__ float lds[LDS_ROWS][CH];   // rows h in [100,160)
    int lane = threadIdx.x;
    int w = blockIdx.x, n = blockIdx.y;
    float wd[9], wu[9];
    #pragma unroll
    for (int j = 0; j < 9; j++) { wd[j] = wdp[j]; wu[j] = wup[j]; }
    float bd = bdp[0], bu = bup[0];
    float* col = A + ((size_t)n * HH * WW + w) * CH + 2*lane;
    const size_t RS = (size_t)WW * CH;

    // ---- down: d[h] = relu(conv(d[h-1]))+x[h] ----
    float2 d;
    float2 rr[16];        // relu(d) for h in [84,100)
    float2 qf[16];
    #pragma unroll
    for (int i = 0; i < 16; i++) qf[i] = *(const float2*)(col + (size_t)i * RS);

    for (int hb = 0; hb < 80; hb += 16) {              // h 0..79 -> global spill
        #pragma unroll
        for (int k = 0; k < 16; k++) {
            int h = hb + k;
            float2 xr = qf[k];
            qf[k] = *(const float2*)(col + (size_t)(h+16) * RS);
            if (h == 0) d = xr;
            else scan_step(d, xr, wd, bd);
            *(float2*)(col + (size_t)h * RS) = make_float2(fmaxf(d.x,0.f), fmaxf(d.y,0.f));
        }
    }
    {   // h 80..95: k<4 global, k>=4 -> rr[k-4]  (rr[j] holds h=84+j)
        #pragma unroll
        for (int k = 0; k < 16; k++) {
            int h = 80 + k;
            float2 xr = qf[k];
            qf[k] = *(const float2*)(col + (size_t)(h+16) * RS);
            scan_step(d, xr, wd, bd);
            float2 rv = make_float2(fmaxf(d.x,0.f), fmaxf(d.y,0.f));
            if (k < 4) *(float2*)(col + (size_t)h * RS) = rv;
            else       rr[k-4] = rv;
        }
    }
    {   // h 96..111: k<4 -> rr[12+k], k>=4 -> LDS row k-4
        #pragma unroll
        for (int k = 0; k < 16; k++) {
            int h = 96 + k;
            float2 xr = qf[k];
            qf[k] = *(const float2*)(col + (size_t)(h+16) * RS);
            scan_step(d, xr, wd, bd);
            float rx = fmaxf(d.x,0.f), ry = fmaxf(d.y,0.f);
            if (k < 4) rr[12+k] = make_float2(rx, ry);
            else { int r = k - 4; lds[r][lane] = rx; lds[r][64+lane] = ry; }
        }
    }
    for (int hb = 112; hb < 160; hb += 16) {           // h 112..159 -> LDS rows 12..59
        #pragma unroll
        for (int k = 0; k < 16; k++) {
            int h = hb + k;
            float2 xr = qf[k];
            if (h + 16 < HH) qf[k] = *(const float2*)(col + (size_t)(h+16) * RS);
            scan_step(d, xr, wd, bd);
            int r = h - 100;
            lds[r][lane] = fmaxf(d.x,0.f); lds[r][64+lane] = fmaxf(d.y,0.f);
        }
    }

    // ---- up: u[s] = relu(conv(u[s-1]))+relu(d[159-s]); 16-deep tf ring ----
    float2 u;
    float2 tf[16];
    #pragma unroll
    for (int k = 0; k < 16; k++) {
        int r = 59 - k;                                // h = 159-k
        tf[k] = make_float2(lds[r][lane], lds[r][64+lane]);
    }
    for (int sb = 0; sb < 32; sb += 16) {              // s 0..31: refill LDS (rows 43..12)
        #pragma unroll
        for (int k = 0; k < 16; k++) {
            int s = sb + k, h = 159 - s;
            float2 t2 = tf[k];
            int r2 = 43 - s;
            tf[k] = make_float2(lds[r2][lane], lds[r2][64+lane]);
            if (s == 0) u = t2;
            else scan_step(u, t2, wu, bu);
            *(float2*)(col + (size_t)h * RS) = u;
        }
    }
    {   // s 32..47: k<12 refill LDS rows 11..0, k>=12 refill rr[27-k] (h2 99..96)
        #pragma unroll
        for (int k = 0; k < 16; k++) {
            int s = 32 + k, h = 159 - s;
            float2 t2 = tf[k];
            if (k < 12) { int r2 = 11 - k; tf[k] = make_float2(lds[r2][lane], lds[r2][64+lane]); }
            else        { tf[k] = rr[27 - k]; }
            scan_step(u, t2, wu, bu);
            *(float2*)(col + (size_t)h * RS) = u;
        }
    }
    {   // s 48..63: k<12 refill rr[11-k] (h2 95..84), k>=12 refill global (h2 83..80)
        #pragma unroll
        for (int k = 0; k < 16; k++) {
            int s = 48 + k, h = 159 - s;
            float2 t2 = tf[k];
            if (k < 12) tf[k] = rr[11 - k];
            else        tf[k] = *(const float2*)(col + (size_t)(95 - k) * RS);
            scan_step(u, t2, wu, bu);
            *(float2*)(col + (size_t)h * RS) = u;
        }
    }
    for (int sb = 64; sb < 144; sb += 16) {            // s 64..143: refill global h-16
        #pragma unroll
        for (int k = 0; k < 16; k++) {
            int s = sb + k, h = 159 - s;
            float2 t2 = tf[k];
            tf[k] = *(const float2*)(col + (size_t)(h - 16) * RS);
            scan_step(u, t2, wu, bu);
            *(float2*)(col + (size_t)h * RS) = u;
        }
    }
    {   // s 144..159: no refill
        #pragma unroll
        for (int k = 0; k < 16; k++) {
            int s = 144 + k, h = 159 - s;
            float2 t2 = tf[k];
            scan_step(u, t2, wu, bu);
            *(float2*)(col + (size_t)h * RS) = u;
        }
    }
}

// K2: fused left+right scan over W + fused flip-transpose output.
// 1 wave per (n,h) row; 5 blocks/CU. Right-scan step s (w=159-s) is the final
// value for out[n][c][159-h][s]; staged into LDS row (179-s)%60 (freed >=16
// steps earlier), flushed coalesced every 32 steps. XOR swizzle col^(row&31).
__global__ __launch_bounds__(64) void k2_horz(float* __restrict__ A,
        const float* __restrict__ wlp, const float* __restrict__ blp,
        const float* __restrict__ wrp, const float* __restrict__ brp,
        float* __restrict__ out) {
    __shared__ float lds[LDS_ROWS][CH];
    int lane = threadIdx.x;
    int hp = blockIdx.x, n = blockIdx.y;
    float wA[9], wB[9];
    #pragma unroll
    for (int j = 0; j < 9; j++) { wA[j] = wlp[j]; wB[j] = wrp[j]; }
    float bA = blp[0], bB = brp[0];
    float* row0 = A + ((size_t)n * HH + hp) * WW * CH + 2*lane;
    const size_t PS = CH;

    // ---- left scan ----
    float2 l;
    float2 rr[16];        // relu(l) for a in [84,100)
    float2 qf[16];
    #pragma unroll
    for (int i = 0; i < 16; i++) qf[i] = *(const float2*)(row0 + (size_t)i * PS);

    for (int ab = 0; ab < 80; ab += 16) {              // a 0..79 -> global spill
        #pragma unroll
        for (int k = 0; k < 16; k++) {
            int a = ab + k;
            float2 xr = qf[k];
            qf[k] = *(const float2*)(row0 + (size_t)(a+16) * PS);
            xr.x = fmaxf(xr.x, 0.f); xr.y = fmaxf(xr.y, 0.f);
            if (a == 0) l = xr;
            else scan_step(l, xr, wA, bA);
            *(float2*)(row0 + (size_t)a * PS) = make_float2(fmaxf(l.x,0.f), fmaxf(l.y,0.f));
        }
    }
    {   // a 80..95: k<4 global, k>=4 -> rr[k-4]
        #pragma unroll
        for (int k = 0; k < 16; k++) {
            int a = 80 + k;
            float2 xr = qf[k];
            qf[k] = *(const float2*)(row0 + (size_t)(a+16) * PS);
            xr.x = fmaxf(xr.x, 0.f); xr.y = fmaxf(xr.y, 0.f);
            scan_step(l, xr, wA, bA);
            float2 rv = make_float2(fmaxf(l.x,0.f), fmaxf(l.y,0.f));
            if (k < 4) *(float2*)(row0 + (size_t)a * PS) = rv;
            else       rr[k-4] = rv;
        }
    }
    {   // a 96..111: k<4 -> rr[12+k], k>=4 -> LDS row k-4 (swizzled)
        #pragma unroll
        for (int k = 0; k < 16; k++) {
            int a = 96 + k;
            float2 xr = qf[k];
            qf[k] = *(const float2*)(row0 + (size_t)(a+16) * PS);
            xr.x = fmaxf(xr.x, 0.f); xr.y = fmaxf(xr.y, 0.f);
            scan_step(l, xr, wA, bA);
            if (k < 4) rr[12+k] = make_float2(fmaxf(l.x,0.f), fmaxf(l.y,0.f));
            else {
                int r = k - 4, sw = r & 31;
                lds[r][lane ^ sw]        = fmaxf(l.x,0.f);
                lds[r][64 + (lane ^ sw)] = fmaxf(l.y,0.f);
            }
        }
    }
    for (int ab = 112; ab < 160; ab += 16) {           // a 112..159 -> LDS rows 12..59
        #pragma unroll
        for (int k = 0; k < 16; k++) {
            int a = ab + k;
            float2 xr = qf[k];
            if (a + 16 < WW) qf[k] = *(const float2*)(row0 + (size_t)(a+16) * PS);
            xr.x = fmaxf(xr.x, 0.f); xr.y = fmaxf(xr.y, 0.f);
            scan_step(l, xr, wA, bA);
            int r = a - 100, sw = r & 31;
            lds[r][lane ^ sw]        = fmaxf(l.x,0.f);
            lds[r][64 + (lane ^ sw)] = fmaxf(l.y,0.f);
        }
    }

    // ---- right scan with fused flipped-transposed output ----
    float2 u;
    float2 tf[16];
    #pragma unroll
    for (int k = 0; k < 16; k++) {
        int r = 59 - k, sw = r & 31;
        tf[k] = make_float2(lds[r][lane ^ sw], lds[r][64 + (lane ^ sw)]);
    }
    int ho  = HH - 1 - hp;
    int l31 = lane & 31;
    int hi  = lane >> 5;
    float* ob = out + ((size_t)(n * CH + hi) * HH + ho) * WW + l31;
    const float* lp = &lds[0][0];

    // staging: final value for step s -> LDS row (179-s)%60 (compile-time per step)
    auto stage = [&](int s, float2 t2) {
        if (s == 0) u = t2;
        else scan_step(u, t2, wB, bB);
        int js = (179 - s) % 60;
        int sw = js & 31;
        lds[js][lane ^ sw]        = fmaxf(u.x, 0.f);
        lds[js][64 + (lane ^ sw)] = fmaxf(u.y, 0.f);
    };
    auto flush = [&](int sb) {   // flush w' = sb..sb+31 for all 128 channels
        int jf = (179 - l31 - sb) % 60; if (jf < 0) jf += 60;
        int jxx = jf & 31;
        int pl = jf * 128 + (hi << 6);
        #pragma unroll
        for (int i = 0; i < 64; i++)
            ob[(size_t)(2*i) * (HH*WW) + sb] = lp[pl + (i ^ jxx)];
    };

    {   // s 0..31: refill LDS rows 43..12
        #pragma unroll
        for (int kk = 0; kk < 32; kk++) {
            int s = kk;
            float2 t2 = tf[kk & 15];
            int r2 = 43 - s, sw = r2 & 31;
            tf[kk & 15] = make_float2(lds[r2][lane ^ sw], lds[r2][64 + (lane ^ sw)]);
            stage(s, t2);
        }
        flush(0);
    }
    {   // s 32..63: kk<12 LDS rows 11..0; kk 12..27 rr[27-kk]; kk>=28 global (a2 83..80)
        #pragma unroll
        for (int kk = 0; kk < 32; kk++) {
            int s = 32 + kk;
            float2 t2 = tf[kk & 15];
            if (kk < 12) {
                int r2 = 11 - kk, sw = r2 & 31;
                tf[kk & 15] = make_float2(lds[r2][lane ^ sw], lds[r2][64 + (lane ^ sw)]);
            } else if (kk < 28) {
                tf[kk & 15] = rr[27 - kk];
            } else {
                tf[kk & 15] = *(const float2*)(row0 + (size_t)(111 - kk) * PS); // a2 = 143-s
            }
            stage(s, t2);
        }
        flush(32);
    }
    for (int sb = 64; sb < 128; sb += 32) {   // s 64..127: refill global a2 = 143-s
        #pragma unroll
        for (int kk = 0; kk < 32; kk++) {
            int s = sb + kk;
            float2 t2 = tf[kk & 15];
            tf[kk & 15] = *(const float2*)(row0 + (size_t)(143 - s) * PS);
            stage(s, t2);
        }
        flush(sb);
    }
    {   // s 128..159: kk<16 refill global (a2 15..0), kk>=16 none
        #pragma unroll
        for (int kk = 0; kk < 32; kk++) {
            int s = 128 + kk;
            float2 t2 = tf[kk & 15];
            if (kk < 16) tf[kk & 15] = *(const float2*)(row0 + (size_t)(15 - kk) * PS);
            stage(s, t2);
        }
        flush(128);
    }
}

extern "C" void kernel_launch(void* const* d_in, const int* in_sizes, int n_in,
                              void* d_out, int out_size, void* d_ws, size_t ws_size,
                              hipStream_t stream) {
    (void)in_sizes; (void)n_in; (void)out_size; (void)ws_size;
    const float* x  = (const float*)d_in[0];
    const float* wd = (const float*)d_in[1];
    const float* bd = (const float*)d_in[2];
    const float* wu = (const float*)d_in[3];
    const float* bu = (const float*)d_in[4];
    const float* wl = (const float*)d_in[5];
    const float* bl = (const float*)d_in[6];
    const float* wr = (const float*)d_in[7];
    const float* br = (const float*)d_in[8];
    float* out = (float*)d_out;
    float* A   = (float*)d_ws;   // needs N*H*W*C*4 = 104,857,600 bytes

    dim3 g0(HH*WW/128, CH/32, NB), b0(256);
    k0_transpose<<<g0, b0, 0, stream>>>(x, A);

    dim3 g1(WW, NB), b1(64);
    k1_vert<<<g1, b1, 0, stream>>>(A, wd, bd, wu, bu);

    dim3 g2(HH, NB);
    k2_horz<<<g2, b1, 0, stream>>>(A, wl, bl, wr, br, out);
}